// Round 3
// baseline (565.309 us; speedup 1.0000x reference)
//
#include <hip/hip_runtime.h>
#include <math.h>

#define TOKENS 16384
#define HIDDEN 4096
#define NEXP   64
#define TPB    512          // 8 waves
#define TOKB   128          // tokens per block (2 per lane)
#define KC     64           // k-chunk staged in LDS
#define EPW    8            // experts per wave
#define PADF4  (KC / 4 + 1) // 17 float4 per row -> conflict-free b128

// transpose weight [64,4096] -> Wt [4096,64] (write-coalesced; W is L2-resident)
__global__ void transpose_w(const float* __restrict__ W, float* __restrict__ Wt) {
    int idx = blockIdx.x * blockDim.x + threadIdx.x;
    int k = idx >> 6;
    int e = idx & 63;
    Wt[idx] = W[(size_t)e * HIDDEN + k];
}

// Pass 1: partial logits over a k-slice. grid = (TOKENS/TOKB, nslices).
// partial layout: [slice][expert][token] so pass-2 reads are lane-coalesced.
__global__ __launch_bounds__(TPB, 8) void router_partial(
    const float* __restrict__ x, const float* __restrict__ Wt,
    float* __restrict__ partial, int kslice)
{
    __shared__ float4 xs[TOKB][PADF4];   // 34816 B -> 4 blocks/CU

    const int tid = threadIdx.x;
    const int t   = tid & 63;                                   // lane
    const int wv  = __builtin_amdgcn_readfirstlane(tid >> 6);   // wave id, uniform
    const int tokenBase = blockIdx.x * TOKB;
    const int kBase = blockIdx.y * kslice;
    const int nch = kslice / KC;

    // staging geometry: lin = tid + r*512 -> tok = lin>>4 (= tok0+32r), kq = lin&15
    const int tok0 = tid >> 4;
    const int kq0  = tid & 15;

    float acca[EPW], accb[EPW];
    #pragma unroll
    for (int j = 0; j < EPW; ++j) { acca[j] = 0.f; accb[j] = 0.f; }

    const float* xp0 = x + (size_t)(tokenBase + tok0) * HIDDEN + kBase + kq0 * 4;
    const float* wk  = Wt + (size_t)kBase * NEXP + wv * EPW;

    // prefetch chunk 0 into registers
    float4 pf[4];
    #pragma unroll
    for (int r = 0; r < 4; ++r)
        pf[r] = *reinterpret_cast<const float4*>(xp0 + (size_t)(32 * r) * HIDDEN);

    for (int c = 0; c < nch; ++c) {
        // commit prefetched chunk to LDS (vmcnt wait lands here, not at barrier)
        #pragma unroll
        for (int r = 0; r < 4; ++r)
            xs[tok0 + 32 * r][kq0] = pf[r];
        __syncthreads();

        // issue next chunk's loads now; they stay in flight across compute
        if (c + 1 < nch) {
            const float* xp = xp0 + (c + 1) * KC;
            #pragma unroll
            for (int r = 0; r < 4; ++r)
                pf[r] = *reinterpret_cast<const float4*>(xp + (size_t)(32 * r) * HIDDEN);
        }

        const float* wp = wk + (size_t)c * KC * NEXP;
        #pragma unroll 8
        for (int kq = 0; kq < KC / 4; ++kq) {
            float4 xa = xs[t][kq];
            float4 xb = xs[t + 64][kq];
            const float* w0 = wp + kq * 4 * NEXP;
            #pragma unroll
            for (int i = 0; i < 4; ++i) {
                const float* wr = w0 + i * NEXP;   // wave-uniform -> s_load_dwordx8
                float xia = (i == 0) ? xa.x : (i == 1) ? xa.y : (i == 2) ? xa.z : xa.w;
                float xib = (i == 0) ? xb.x : (i == 1) ? xb.y : (i == 2) ? xb.z : xb.w;
                #pragma unroll
                for (int j = 0; j < EPW; ++j) {
                    acca[j] = fmaf(xia, wr[j], acca[j]);
                    accb[j] = fmaf(xib, wr[j], accb[j]);
                }
            }
        }
        __syncthreads();
    }

    // write partials: per (wave, j): 64 consecutive tokens -> coalesced
    float* pbase = partial + ((size_t)blockIdx.y * NEXP + wv * EPW) * TOKENS
                 + tokenBase + t;
    #pragma unroll
    for (int j = 0; j < EPW; ++j) {
        pbase[(size_t)j * TOKENS]      = acca[j];
        pbase[(size_t)j * TOKENS + 64] = accb[j];
    }
}

// Pass 2: sum slices, top-2, softmax. One thread per token; reads coalesced.
__global__ void reduce_topk(const float* __restrict__ partial,
                            float* __restrict__ out, int nslices)
{
    int t = blockIdx.x * blockDim.x + threadIdx.x;
    float v1 = -INFINITY, v2 = -INFINITY;
    int i1 = 0, i2 = 0;
    #pragma unroll 4
    for (int e = 0; e < NEXP; ++e) {
        float v = 0.f;
        for (int s = 0; s < nslices; ++s)          // fixed order: deterministic
            v += partial[((size_t)s * NEXP + e) * TOKENS + t];
        if (v > v1)      { v2 = v1; i2 = i1; v1 = v; i1 = e; }
        else if (v > v2) { v2 = v;  i2 = e; }
    }
    float e2 = expf(v2 - v1);
    float d  = 1.f / (1.f + e2);
    out[t * 2 + 0] = d;
    out[t * 2 + 1] = e2 * d;
    out[2 * TOKENS + t * 2 + 0] = (float)i1;
    out[2 * TOKENS + t * 2 + 1] = (float)i2;
}

extern "C" void kernel_launch(void* const* d_in, const int* in_sizes, int n_in,
                              void* d_out, int out_size, void* d_ws, size_t ws_size,
                              hipStream_t stream) {
    const float* x = (const float*)d_in[0];     // [16384, 4096]
    const float* W = (const float*)d_in[1];     // [64, 4096]
    float* out = (float*)d_out;
    float* Wt  = (float*)d_ws;                                  // 1 MB
    float* partial = Wt + (size_t)NEXP * HIDDEN;

    const size_t wtBytes = (size_t)NEXP * HIDDEN * sizeof(float);
    const size_t sliceBytes = (size_t)NEXP * TOKENS * sizeof(float);  // 4 MB
    int nsl;
    if      (ws_size >= wtBytes + 8 * sliceBytes) nsl = 8;   // grid 1024 -> 4 blk/CU
    else if (ws_size >= wtBytes + 4 * sliceBytes) nsl = 4;
    else if (ws_size >= wtBytes + 2 * sliceBytes) nsl = 2;
    else                                          nsl = 1;
    const int kslice = HIDDEN / nsl;

    transpose_w<<<(NEXP * HIDDEN) / 256, 256, 0, stream>>>(W, Wt);
    dim3 grid(TOKENS / TOKB, nsl);
    router_partial<<<grid, TPB, 0, stream>>>(x, Wt, partial, kslice);
    reduce_topk<<<TOKENS / 64, 64, 0, stream>>>(partial, out, nsl);
}

// Round 4
// 421.423 us; speedup vs baseline: 1.3414x; 1.3414x over previous
//
#include <hip/hip_runtime.h>
#include <math.h>

#define TOKENS 16384
#define HIDDEN 4096
#define NEXP   64
#define NSL    4                 // k-split: grid.y slices
#define KSL    (HIDDEN / NSL)    // 1024 k per slice
#define TOKB   64                // tokens per block (4 waves x 16)
#define NCH    (KSL / 32)        // 32 mfma k-chunks per slice

typedef _Float16 half8 __attribute__((ext_vector_type(8)));
typedef float    f32x4 __attribute__((ext_vector_type(4)));

// Pre-pack W [64][4096] fp32 -> Wh/Wl fp16 in MFMA B-layout [kblock][expert][32k]
__global__ void w_prep(const float* __restrict__ W,
                       _Float16* __restrict__ Wh, _Float16* __restrict__ Wl) {
    int idx = blockIdx.x * blockDim.x + threadIdx.x;   // = e*4096 + k
    int e = idx >> 12;
    int k = idx & 4095;
    float v = W[idx];
    _Float16 h = (_Float16)v;                // RTN, 11-bit mantissa
    _Float16 l = (_Float16)(v - (float)h);   // residual: x-h exact in fp32
    size_t dst = (((size_t)(k >> 5) * NEXP) + e) * 32 + (k & 31);
    Wh[dst] = h;
    Wl[dst] = l;
}

// logits via fp16 hi/lo split MFMA: acc += Al*Bh + Ah*Bl + Ah*Bh  (l*l dropped)
// No LDS, no barriers: waves stream x independently; W hits L2.
__global__ __launch_bounds__(256, 4) void router_mfma(
    const float* __restrict__ x, const _Float16* __restrict__ Wh,
    const _Float16* __restrict__ Wl, float* __restrict__ partial)
{
    const int tid  = threadIdx.x;
    const int lane = tid & 63;
    const int wv   = tid >> 6;       // 0..3
    const int e16  = lane & 15;      // A: token row; B: expert row; D: col
    const int quad = lane >> 4;

    const int tok0 = blockIdx.x * TOKB + wv * 16;
    const int sl   = blockIdx.y;
    const int kb0  = sl * (KSL / 32);

    f32x4 acc[4];
    #pragma unroll
    for (int n = 0; n < 4; ++n) acc[n] = (f32x4){0.f, 0.f, 0.f, 0.f};

    // A-operand: lane holds x[tok0+e16][k0 + quad*8 + j], j=0..7 (32B contiguous)
    const float* xp = x + (size_t)(tok0 + e16) * HIDDEN + sl * KSL + quad * 8;

    float4 pa0 = *(const float4*)(xp);
    float4 pa1 = *(const float4*)(xp + 4);

    for (int c = 0; c < NCH; ++c) {
        float av[8] = {pa0.x, pa0.y, pa0.z, pa0.w, pa1.x, pa1.y, pa1.z, pa1.w};
        if (c + 1 < NCH) {           // prefetch next chunk; stays in flight
            pa0 = *(const float4*)(xp + (c + 1) * 32);
            pa1 = *(const float4*)(xp + (c + 1) * 32 + 4);
        }

        // B frags: [kblock][expert][32k] -> 64 lanes read 1KB contiguous (L2)
        const size_t bo = (((size_t)(kb0 + c) * NEXP) + e16) * 32 + quad * 8;
        half8 bh[4], bl[4];
        #pragma unroll
        for (int n = 0; n < 4; ++n) {
            bh[n] = *reinterpret_cast<const half8*>(Wh + bo + (size_t)n * 16 * 32);
            bl[n] = *reinterpret_cast<const half8*>(Wl + bo + (size_t)n * 16 * 32);
        }

        // fp32 -> f16 hi/lo split
        half8 ah, al;
        #pragma unroll
        for (int j = 0; j < 8; ++j) {
            _Float16 h = (_Float16)av[j];
            ah[j] = h;
            al[j] = (_Float16)(av[j] - (float)h);
        }

        // 4 independent chains of 3 dependent MFMAs (small terms first)
        #pragma unroll
        for (int n = 0; n < 4; ++n)
            acc[n] = __builtin_amdgcn_mfma_f32_16x16x32_f16(al, bh[n], acc[n], 0, 0, 0);
        #pragma unroll
        for (int n = 0; n < 4; ++n)
            acc[n] = __builtin_amdgcn_mfma_f32_16x16x32_f16(ah, bl[n], acc[n], 0, 0, 0);
        #pragma unroll
        for (int n = 0; n < 4; ++n)
            acc[n] = __builtin_amdgcn_mfma_f32_16x16x32_f16(ah, bh[n], acc[n], 0, 0, 0);
    }

    // D layout: token = tok0 + quad*4 + r, expert = n*16 + e16
    // partial layout [slice][expert][token] -> 16B store per lane
    #pragma unroll
    for (int n = 0; n < 4; ++n) {
        float* pb = partial + ((size_t)sl * NEXP + n * 16 + e16) * TOKENS
                  + tok0 + quad * 4;
        *reinterpret_cast<float4*>(pb) =
            make_float4(acc[n][0], acc[n][1], acc[n][2], acc[n][3]);
    }
}

// Pass 2: sum slices, top-2, softmax. One thread per token; reads coalesced.
__global__ void reduce_topk(const float* __restrict__ partial,
                            float* __restrict__ out)
{
    int t = blockIdx.x * blockDim.x + threadIdx.x;
    float v1 = -INFINITY, v2 = -INFINITY;
    int i1 = 0, i2 = 0;
    #pragma unroll 4
    for (int e = 0; e < NEXP; ++e) {
        float v = 0.f;
        #pragma unroll
        for (int s = 0; s < NSL; ++s)            // fixed order: deterministic
            v += partial[((size_t)s * NEXP + e) * TOKENS + t];
        if (v > v1)      { v2 = v1; i2 = i1; v1 = v; i1 = e; }
        else if (v > v2) { v2 = v;  i2 = e; }
    }
    float e2 = expf(v2 - v1);
    float d  = 1.f / (1.f + e2);
    out[t * 2 + 0] = d;
    out[t * 2 + 1] = e2 * d;
    out[2 * TOKENS + t * 2 + 0] = (float)i1;
    out[2 * TOKENS + t * 2 + 1] = (float)i2;
}

extern "C" void kernel_launch(void* const* d_in, const int* in_sizes, int n_in,
                              void* d_out, int out_size, void* d_ws, size_t ws_size,
                              hipStream_t stream) {
    const float* x = (const float*)d_in[0];     // [16384, 4096]
    const float* W = (const float*)d_in[1];     // [64, 4096]
    float* out = (float*)d_out;

    _Float16* Wh = (_Float16*)d_ws;                       // 512 KB
    _Float16* Wl = Wh + (size_t)NEXP * HIDDEN;            // 512 KB
    float* partial = (float*)((char*)d_ws + 2 * (size_t)NEXP * HIDDEN * sizeof(_Float16));
    // partial: NSL*64*16384*4 = 16 MB (ws >= 33 MB per R2 probe)

    w_prep<<<(NEXP * HIDDEN) / 256, 256, 0, stream>>>(W, Wh, Wl);
    dim3 grid(TOKENS / TOKB, NSL);
    router_mfma<<<grid, 256, 0, stream>>>(x, Wh, Wl, partial);
    reduce_topk<<<TOKENS / 256, 256, 0, stream>>>(partial, out);
}

// Round 5
// 404.355 us; speedup vs baseline: 1.3981x; 1.0422x over previous
//
#include <hip/hip_runtime.h>
#include <math.h>

#define TOKENS 16384
#define HIDDEN 4096
#define NEXP   64
#define NSL    8                 // k-split: grid.y slices (ws = 1 GiB, 32 MB partial OK)
#define KSL    (HIDDEN / NSL)    // 512 k per slice
#define TOKB   128               // tokens per block: 4 waves x 32 (2 per lane-row)
#define NCH    (KSL / 32)        // 16 mfma k-chunks per slice

typedef _Float16 half8 __attribute__((ext_vector_type(8)));
typedef float    f32x4 __attribute__((ext_vector_type(4)));

// Pre-pack W [64][4096] fp32 -> Wh/Wl fp16 in MFMA B-layout [kblock][expert][32k]
__global__ void w_prep(const float* __restrict__ W,
                       _Float16* __restrict__ Wh, _Float16* __restrict__ Wl) {
    int idx = blockIdx.x * blockDim.x + threadIdx.x;   // = e*4096 + k
    int e = idx >> 12;
    int k = idx & 4095;
    float v = W[idx];
    _Float16 h = (_Float16)v;                // RTN, 11-bit mantissa
    _Float16 l = (_Float16)(v - (float)h);   // residual
    size_t dst = (((size_t)(k >> 5) * NEXP) + e) * 32 + (k & 31);
    Wh[dst] = h;
    Wl[dst] = l;
}

__device__ __forceinline__ void split8(const float4& p0, const float4& p1,
                                       half8& h, half8& l) {
    const float v[8] = {p0.x, p0.y, p0.z, p0.w, p1.x, p1.y, p1.z, p1.w};
    #pragma unroll
    for (int j = 0; j < 8; ++j) {
        _Float16 hi = (_Float16)v[j];
        h[j] = hi;
        l[j] = (_Float16)(v[j] - (float)hi);
    }
}

// logits via fp16 hi/lo split MFMA: acc += Al*Bh + Ah*Bl + Ah*Bh  (l*l dropped).
// 2 token-fragments per wave share each B fragment (halves L2 B-traffic).
__global__ __launch_bounds__(256, 4) void router_mfma(
    const float* __restrict__ x, const _Float16* __restrict__ Wh,
    const _Float16* __restrict__ Wl, float* __restrict__ partial)
{
    const int tid  = threadIdx.x;
    const int lane = tid & 63;
    const int wv   = tid >> 6;       // 0..3
    const int e16  = lane & 15;
    const int quad = lane >> 4;

    const int tok0 = blockIdx.x * TOKB + wv * 32;
    const int sl   = blockIdx.y;
    const int kb0  = sl * NCH;

    f32x4 accA[4], accB[4];
    #pragma unroll
    for (int n = 0; n < 4; ++n) {
        accA[n] = (f32x4){0.f, 0.f, 0.f, 0.f};
        accB[n] = (f32x4){0.f, 0.f, 0.f, 0.f};
    }

    // A: lane holds x[row][k0 + quad*8 + j]; frag A rows tok0+e16, frag B +16
    const float* xpA = x + (size_t)(tok0 + e16) * HIDDEN + sl * KSL + quad * 8;
    const float* xpB = xpA + (size_t)16 * HIDDEN;

    float4 pA0 = *(const float4*)(xpA),     pA1 = *(const float4*)(xpA + 4);
    float4 pB0 = *(const float4*)(xpB),     pB1 = *(const float4*)(xpB + 4);

    for (int c = 0; c < NCH; ++c) {
        // B frags: [kblock][expert][32k] -> wave reads contiguous 1KB runs (L2)
        const size_t bo = (((size_t)(kb0 + c) * NEXP) + e16) * 32 + quad * 8;
        half8 bh[4], bl[4];
        #pragma unroll
        for (int n = 0; n < 4; ++n) {
            bh[n] = *reinterpret_cast<const half8*>(Wh + bo + (size_t)n * 16 * 32);
            bl[n] = *reinterpret_cast<const half8*>(Wl + bo + (size_t)n * 16 * 32);
        }

        // split current A regs, then immediately re-use them as prefetch regs
        half8 ahA, alA, ahB, alB;
        split8(pA0, pA1, ahA, alA);
        split8(pB0, pB1, ahB, alB);
        if (c + 1 < NCH) {
            pA0 = *(const float4*)(xpA + (c + 1) * 32);
            pA1 = *(const float4*)(xpA + (c + 1) * 32 + 4);
            pB0 = *(const float4*)(xpB + (c + 1) * 32);
            pB1 = *(const float4*)(xpB + (c + 1) * 32 + 4);
        }

        // 8 chains x 3 dependent MFMAs; >=7 independent ops between links
        #pragma unroll
        for (int n = 0; n < 4; ++n)
            accA[n] = __builtin_amdgcn_mfma_f32_16x16x32_f16(alA, bh[n], accA[n], 0, 0, 0);
        #pragma unroll
        for (int n = 0; n < 4; ++n)
            accB[n] = __builtin_amdgcn_mfma_f32_16x16x32_f16(alB, bh[n], accB[n], 0, 0, 0);
        #pragma unroll
        for (int n = 0; n < 4; ++n)
            accA[n] = __builtin_amdgcn_mfma_f32_16x16x32_f16(ahA, bl[n], accA[n], 0, 0, 0);
        #pragma unroll
        for (int n = 0; n < 4; ++n)
            accB[n] = __builtin_amdgcn_mfma_f32_16x16x32_f16(ahB, bl[n], accB[n], 0, 0, 0);
        #pragma unroll
        for (int n = 0; n < 4; ++n)
            accA[n] = __builtin_amdgcn_mfma_f32_16x16x32_f16(ahA, bh[n], accA[n], 0, 0, 0);
        #pragma unroll
        for (int n = 0; n < 4; ++n)
            accB[n] = __builtin_amdgcn_mfma_f32_16x16x32_f16(ahB, bh[n], accB[n], 0, 0, 0);
    }

    // D: col = n*16+e16 (expert), row = quad*4+r (token). 16B stores.
    #pragma unroll
    for (int n = 0; n < 4; ++n) {
        float* pb = partial + ((size_t)sl * NEXP + n * 16 + e16) * TOKENS
                  + tok0 + quad * 4;
        *reinterpret_cast<float4*>(pb) =
            make_float4(accA[n][0], accA[n][1], accA[n][2], accA[n][3]);
        *reinterpret_cast<float4*>(pb + 16) =
            make_float4(accB[n][0], accB[n][1], accB[n][2], accB[n][3]);
    }
}

// Pass 2: sum slices, top-2, softmax. One thread per token; reads coalesced.
__global__ void reduce_topk(const float* __restrict__ partial,
                            float* __restrict__ out)
{
    int t = blockIdx.x * blockDim.x + threadIdx.x;
    float v1 = -INFINITY, v2 = -INFINITY;
    int i1 = 0, i2 = 0;
    #pragma unroll 4
    for (int e = 0; e < NEXP; ++e) {
        float v = 0.f;
        #pragma unroll
        for (int s = 0; s < NSL; ++s)            // fixed order: deterministic
            v += partial[((size_t)s * NEXP + e) * TOKENS + t];
        if (v > v1)      { v2 = v1; i2 = i1; v1 = v; i1 = e; }
        else if (v > v2) { v2 = v;  i2 = e; }
    }
    float e2 = expf(v2 - v1);
    float d  = 1.f / (1.f + e2);
    out[t * 2 + 0] = d;
    out[t * 2 + 1] = e2 * d;
    out[2 * TOKENS + t * 2 + 0] = (float)i1;
    out[2 * TOKENS + t * 2 + 1] = (float)i2;
}

extern "C" void kernel_launch(void* const* d_in, const int* in_sizes, int n_in,
                              void* d_out, int out_size, void* d_ws, size_t ws_size,
                              hipStream_t stream) {
    const float* x = (const float*)d_in[0];     // [16384, 4096]
    const float* W = (const float*)d_in[1];     // [64, 4096]
    float* out = (float*)d_out;

    _Float16* Wh = (_Float16*)d_ws;                       // 512 KB
    _Float16* Wl = Wh + (size_t)NEXP * HIDDEN;            // 512 KB
    float* partial = (float*)((char*)d_ws + 2 * (size_t)NEXP * HIDDEN * sizeof(_Float16));
    // partial: NSL*64*16384*4 = 32 MB (ws = 1 GiB per R4 fill evidence)

    w_prep<<<(NEXP * HIDDEN) / 256, 256, 0, stream>>>(W, Wh, Wl);
    dim3 grid(TOKENS / TOKB, NSL);
    router_mfma<<<grid, 256, 0, stream>>>(x, Wh, Wl, partial);
    reduce_topk<<<TOKENS / 128, 128, 0, stream>>>(partial, out);
}